// Round 3
// baseline (3490.989 us; speedup 1.0000x reference)
//
#include <hip/hip_runtime.h>

#define BATCH   8
#define NPTS    16384
#define NCH     128
#define NPOINT  1024
#define NSAMPLE 64
#define CIN     131   // 3 + NCH

// ---------------------------------------------------------------------------
// Furthest point sampling: one block (1024 threads) per batch.
// Bit-exact vs numpy: d = ((dx*dx + dy*dy) + dz*dz) with no FMA contraction,
// min-dist update via fminf, argmax = first occurrence (tie -> lowest index).
// Also emits new_xyz (gather of selected coords) and inds as float.
// ---------------------------------------------------------------------------
__global__ __launch_bounds__(1024) void fps_kernel(
    const float* __restrict__ xyz, float* __restrict__ out_newxyz,
    float* __restrict__ out_inds_f)
{
  const int b = blockIdx.x;
  const int t = threadIdx.x;
  const float* __restrict__ p = xyz + (size_t)b * NPTS * 3;

  float xs[16], ys[16], zs[16], mind[16];
#pragma unroll
  for (int i = 0; i < 16; ++i) {
    const int n = t + i * 1024;           // contiguous per wave -> coalesced
    xs[i] = p[n * 3 + 0];
    ys[i] = p[n * 3 + 1];
    zs[i] = p[n * 3 + 2];
    mind[i] = 1e10f;
  }

  __shared__ float s_px, s_py, s_pz;
  __shared__ float s_wval[16];
  __shared__ int   s_widx[16];

  if (t == 0) {
    s_px = p[0]; s_py = p[1]; s_pz = p[2];
    out_inds_f[b * NPOINT] = 0.0f;
    size_t o = (size_t)b * NPOINT * 3;
    out_newxyz[o + 0] = p[0];
    out_newxyz[o + 1] = p[1];
    out_newxyz[o + 2] = p[2];
  }
  __syncthreads();
  float px = s_px, py = s_py, pz = s_pz;

  for (int k = 1; k < NPOINT; ++k) {
    float bestv = -1.0f;
    int   besti = 0;
#pragma unroll
    for (int i = 0; i < 16; ++i) {
      const float dx = xs[i] - px;
      const float dy = ys[i] - py;
      const float dz = zs[i] - pz;
      // exact numpy order, no fma contraction:
      const float d = __fadd_rn(__fadd_rn(__fmul_rn(dx, dx), __fmul_rn(dy, dy)),
                                __fmul_rn(dz, dz));
      const float m = fminf(mind[i], d);
      mind[i] = m;
      if (m > bestv) { bestv = m; besti = t + i * 1024; }
    }
    // wave (64-lane) argmax reduce, tie -> lowest index
#pragma unroll
    for (int off = 32; off >= 1; off >>= 1) {
      const float ov = __shfl_xor(bestv, off, 64);
      const int   oi = __shfl_xor(besti, off, 64);
      if (ov > bestv || (ov == bestv && oi < besti)) { bestv = ov; besti = oi; }
    }
    const int wid = t >> 6;
    if ((t & 63) == 0) { s_wval[wid] = bestv; s_widx[wid] = besti; }
    __syncthreads();
    if (t == 0) {
      float bv = s_wval[0];
      int   bi = s_widx[0];
#pragma unroll
      for (int w = 1; w < 16; ++w) {
        const float v = s_wval[w];
        const int  ii = s_widx[w];
        if (v > bv || (v == bv && ii < bi)) { bv = v; bi = ii; }
      }
      const float qx = p[bi * 3 + 0], qy = p[bi * 3 + 1], qz = p[bi * 3 + 2];
      s_px = qx; s_py = qy; s_pz = qz;
      out_inds_f[b * NPOINT + k] = (float)bi;
      const size_t o = ((size_t)b * NPOINT + k) * 3;
      out_newxyz[o + 0] = qx; out_newxyz[o + 1] = qy; out_newxyz[o + 2] = qz;
    }
    __syncthreads();
    px = s_px; py = s_py; pz = s_pz;
  }
}

// ---------------------------------------------------------------------------
// Transpose weights into [ic][oc] layout so MLP threads can float4-load
// 4 (or 8) output channels per K-step.
// ---------------------------------------------------------------------------
__global__ void wtrans_kernel(const float* __restrict__ W0,
                              const float* __restrict__ W1,
                              const float* __restrict__ W2,
                              float* __restrict__ w0t,
                              float* __restrict__ w1t,
                              float* __restrict__ w2t)
{
  const int t = blockIdx.x * blockDim.x + threadIdx.x;
  if (t < 64 * CIN) { const int oc = t / CIN, ic = t % CIN; w0t[ic * 64  + oc] = W0[t]; }
  if (t < 64 * 64)  { const int oc = t >> 6,  ic = t & 63;  w1t[ic * 64  + oc] = W1[t]; }
  if (t < 128 * 64) { const int oc = t / 64,  ic = t % 64;  w2t[ic * 128 + oc] = W2[t]; }
}

// ---------------------------------------------------------------------------
// Ball query: one wave per center. First NSAMPLE indices (ascending) with
// d2 < r^2; pad remaining slots with the first in-ball index.
// ---------------------------------------------------------------------------
__global__ __launch_bounds__(256) void ballquery_kernel(
    const float* __restrict__ xyz, const float* __restrict__ newxyz,
    int* __restrict__ ballidx)
{
  const int gw   = (blockIdx.x * 256 + threadIdx.x) >> 6;  // global wave = center
  const int lane = threadIdx.x & 63;
  const int b    = gw >> 10;
  const float R2 = (float)(0.3 * 0.3);   // fl32(0.09), matches numpy weak cast

  const float cx = newxyz[gw * 3 + 0];
  const float cy = newxyz[gw * 3 + 1];
  const float cz = newxyz[gw * 3 + 2];
  const float* __restrict__ p = xyz + (size_t)b * NPTS * 3;
  int* __restrict__ out = ballidx + (size_t)gw * NSAMPLE;

  int cnt = 0, first = -1;
  for (int base = 0; base < NPTS; base += 64) {
    const int n = base + lane;
    const float dx = p[n * 3 + 0] - cx;
    const float dy = p[n * 3 + 1] - cy;
    const float dz = p[n * 3 + 2] - cz;
    const float d = __fadd_rn(__fadd_rn(__fmul_rn(dx, dx), __fmul_rn(dy, dy)),
                              __fmul_rn(dz, dz));
    const bool in = d < R2;
    const unsigned long long m = __ballot(in);
    if (first < 0 && m) first = base + __ffsll(m) - 1;
    const int pos = __popcll(m & ((1ull << lane) - 1ull));
    if (in && cnt + pos < NSAMPLE) out[cnt + pos] = n;
    cnt += __popcll(m);
    if (cnt >= NSAMPLE) break;
  }
  const int c = cnt < NSAMPLE ? cnt : NSAMPLE;
  for (int j = c + lane; j < NSAMPLE; j += 64) out[j] = first;
}

// ---------------------------------------------------------------------------
// Grouping + SharedMLP (131->64->64->128, ReLU) + max-pool over samples.
// One block (256 threads) per center. x staged in LDS [ch][64]; weights read
// from global transposed layout; bias folded into acc init; ReLU once after
// the max-pool (monotone => commutes).
// ---------------------------------------------------------------------------
__global__ __launch_bounds__(256) void mlp_kernel(
    const float* __restrict__ xyz, const float* __restrict__ feat,
    const float* __restrict__ newxyz, const int* __restrict__ ballidx,
    const float* __restrict__ w0t, const float* __restrict__ b0,
    const float* __restrict__ w1t, const float* __restrict__ b1,
    const float* __restrict__ w2t, const float* __restrict__ b2,
    float* __restrict__ out_feat)
{
  __shared__ float sA[CIN * 64];   // x (131x64); reused as h2 (64x64)
  __shared__ float sB[64 * 64];    // h1
  __shared__ int   s_idx[NSAMPLE];

  const int blk = blockIdx.x;
  const int b = blk >> 10, pc = blk & 1023;
  const int t = threadIdx.x;

  if (t < NSAMPLE) s_idx[t] = ballidx[(size_t)blk * NSAMPLE + t];
  __syncthreads();

  const int s = t & 63, cg = t >> 6;
  const int is = s_idx[s];
  const float* __restrict__ pb = xyz + (size_t)b * NPTS * 3;
  if (cg == 0) {
    const float cx = newxyz[blk * 3 + 0];
    const float cy = newxyz[blk * 3 + 1];
    const float cz = newxyz[blk * 3 + 2];
    sA[0 * 64 + s] = pb[is * 3 + 0] - cx;
    sA[1 * 64 + s] = pb[is * 3 + 1] - cy;
    sA[2 * 64 + s] = pb[is * 3 + 2] - cz;
  }
  const float* __restrict__ fb = feat + (size_t)b * NCH * NPTS;
  for (int c = cg; c < NCH; c += 4)
    sA[(3 + c) * 64 + s] = fb[(size_t)c * NPTS + is];
  __syncthreads();

  const int s0  = (t & 15) * 4;   // 4 samples
  const int oc0 = (t >> 4) * 4;   // 4 out-channels (layers 1,2)

  // ---- layer 1: CIN -> 64  (sA -> sB)
  {
    float acc[4][4];
#pragma unroll
    for (int j = 0; j < 4; ++j) {
      const float bj = b0[oc0 + j];
#pragma unroll
      for (int i = 0; i < 4; ++i) acc[i][j] = bj;
    }
    for (int ic = 0; ic < CIN; ++ic) {
      const float4 xv = *(const float4*)&sA[ic * 64 + s0];
      const float4 wv = *(const float4*)&w0t[ic * 64 + oc0];
      const float xr[4] = {xv.x, xv.y, xv.z, xv.w};
      const float wr[4] = {wv.x, wv.y, wv.z, wv.w};
#pragma unroll
      for (int i = 0; i < 4; ++i)
#pragma unroll
        for (int j = 0; j < 4; ++j) acc[i][j] += xr[i] * wr[j];
    }
#pragma unroll
    for (int j = 0; j < 4; ++j) {
      float4 r;
      r.x = fmaxf(acc[0][j], 0.f); r.y = fmaxf(acc[1][j], 0.f);
      r.z = fmaxf(acc[2][j], 0.f); r.w = fmaxf(acc[3][j], 0.f);
      *(float4*)&sB[(oc0 + j) * 64 + s0] = r;
    }
  }
  __syncthreads();

  // ---- layer 2: 64 -> 64  (sB -> sA, x is dead)
  {
    float acc[4][4];
#pragma unroll
    for (int j = 0; j < 4; ++j) {
      const float bj = b1[oc0 + j];
#pragma unroll
      for (int i = 0; i < 4; ++i) acc[i][j] = bj;
    }
    for (int ic = 0; ic < 64; ++ic) {
      const float4 xv = *(const float4*)&sB[ic * 64 + s0];
      const float4 wv = *(const float4*)&w1t[ic * 64 + oc0];
      const float xr[4] = {xv.x, xv.y, xv.z, xv.w};
      const float wr[4] = {wv.x, wv.y, wv.z, wv.w};
#pragma unroll
      for (int i = 0; i < 4; ++i)
#pragma unroll
        for (int j = 0; j < 4; ++j) acc[i][j] += xr[i] * wr[j];
    }
#pragma unroll
    for (int j = 0; j < 4; ++j) {
      float4 r;
      r.x = fmaxf(acc[0][j], 0.f); r.y = fmaxf(acc[1][j], 0.f);
      r.z = fmaxf(acc[2][j], 0.f); r.w = fmaxf(acc[3][j], 0.f);
      *(float4*)&sA[(oc0 + j) * 64 + s0] = r;
    }
  }
  __syncthreads();

  // ---- layer 3: 64 -> 128 + max-pool over 64 samples
  const int oc8 = (t >> 4) * 8;
  float acc[4][8];
#pragma unroll
  for (int j = 0; j < 8; ++j) {
    const float bj = b2[oc8 + j];
#pragma unroll
    for (int i = 0; i < 4; ++i) acc[i][j] = bj;
  }
  for (int ic = 0; ic < 64; ++ic) {
    const float4 xv  = *(const float4*)&sA[ic * 64 + s0];
    const float4 wlo = *(const float4*)&w2t[ic * 128 + oc8];
    const float4 whi = *(const float4*)&w2t[ic * 128 + oc8 + 4];
    const float xr[4] = {xv.x, xv.y, xv.z, xv.w};
    const float wr[8] = {wlo.x, wlo.y, wlo.z, wlo.w, whi.x, whi.y, whi.z, whi.w};
#pragma unroll
    for (int i = 0; i < 4; ++i)
#pragma unroll
      for (int j = 0; j < 8; ++j) acc[i][j] += xr[i] * wr[j];
  }
  float m[8];
#pragma unroll
  for (int j = 0; j < 8; ++j)
    m[j] = fmaxf(fmaxf(acc[0][j], acc[1][j]), fmaxf(acc[2][j], acc[3][j]));
#pragma unroll
  for (int off = 8; off >= 1; off >>= 1) {
#pragma unroll
    for (int j = 0; j < 8; ++j)
      m[j] = fmaxf(m[j], __shfl_xor(m[j], off, 64));
  }
  if ((t & 15) == 0) {
#pragma unroll
    for (int j = 0; j < 8; ++j)
      out_feat[((size_t)b * NCH + oc8 + j) * NPOINT + pc] = fmaxf(m[j], 0.f);
  }
}

// ---------------------------------------------------------------------------
extern "C" void kernel_launch(void* const* d_in, const int* in_sizes, int n_in,
                              void* d_out, int out_size, void* d_ws, size_t ws_size,
                              hipStream_t stream)
{
  const float* xyz  = (const float*)d_in[0];
  const float* feat = (const float*)d_in[1];
  const float* W0   = (const float*)d_in[2];
  const float* b0   = (const float*)d_in[3];
  const float* W1   = (const float*)d_in[4];
  const float* b1   = (const float*)d_in[5];
  const float* W2   = (const float*)d_in[6];
  const float* b2   = (const float*)d_in[7];

  float* out_newxyz = (float*)d_out;                               // 8*1024*3
  float* out_feat   = out_newxyz + (size_t)BATCH * NPOINT * 3;     // 8*128*1024
  float* out_inds_f = out_feat + (size_t)BATCH * NCH * NPOINT;     // 8*1024

  char* ws = (char*)d_ws;
  int*   ballidx = (int*)ws;                                       // 2 MB
  float* w0t = (float*)(ws + (size_t)BATCH * NPOINT * NSAMPLE * 4);
  float* w1t = w0t + 64 * CIN;
  float* w2t = w1t + 64 * 64;

  fps_kernel<<<dim3(BATCH), dim3(1024), 0, stream>>>(xyz, out_newxyz, out_inds_f);
  wtrans_kernel<<<dim3((64 * CIN + 255) / 256), dim3(256), 0, stream>>>(
      W0, W1, W2, w0t, w1t, w2t);
  ballquery_kernel<<<dim3(BATCH * NPOINT / 4), dim3(256), 0, stream>>>(
      xyz, out_newxyz, ballidx);
  mlp_kernel<<<dim3(BATCH * NPOINT), dim3(256), 0, stream>>>(
      xyz, feat, out_newxyz, ballidx, w0t, b0, w1t, b1, w2t, b2, out_feat);
}

// Round 4
// 2866.439 us; speedup vs baseline: 1.2179x; 1.2179x over previous
//
#include <hip/hip_runtime.h>

#define BATCH   8
#define NPTS    16384
#define NCH     128
#define NPOINT  1024
#define NSAMPLE 64
#define CIN     131   // 3 + NCH

// ---------------------------------------------------------------------------
// Furthest point sampling: one block (512 threads, 8 waves) per batch.
// Bit-exact vs numpy: d = ((dx*dx + dy*dy) + dz*dz) with no FMA contraction,
// fminf min-dist update, argmax first-occurrence (lowest flat index on ties).
// Critical-path design: ONE barrier per iteration; wave leaders post (v,idx)
// to parity double-buffered LDS slots; all threads redundantly scan the 8
// slots; next point's coords come from a uniform (broadcast) global load.
// ---------------------------------------------------------------------------
__global__ __launch_bounds__(512) void fps_kernel(
    const float* __restrict__ xyz, float* __restrict__ out_newxyz,
    float* __restrict__ out_inds_f)
{
  const int b = blockIdx.x;
  const int t = threadIdx.x;
  const float* __restrict__ p = xyz + (size_t)b * NPTS * 3;

  // 32 points per thread, layout n = t + i*512 (coalesced per wave)
  float xs[32], ys[32], zs[32], mind[32];
#pragma unroll
  for (int i = 0; i < 32; ++i) {
    const int n = t + i * 512;
    xs[i] = p[n * 3 + 0];
    ys[i] = p[n * 3 + 1];
    zs[i] = p[n * 3 + 2];
    mind[i] = 1e10f;
  }

  __shared__ float s_v[2][8];
  __shared__ int   s_i[2][8];

  // k = 0: point 0, coords read uniformly by all threads
  float px = p[0], py = p[1], pz = p[2];
  if (t == 0) {
    out_inds_f[b * NPOINT] = 0.0f;
    const size_t o = (size_t)b * NPOINT * 3;
    out_newxyz[o + 0] = px; out_newxyz[o + 1] = py; out_newxyz[o + 2] = pz;
  }

  for (int k = 1; k < NPOINT; ++k) {
    const int par = k & 1;

    float bestv = -1.0f;
    int   besti = 0;
#pragma unroll
    for (int i = 0; i < 32; ++i) {
      const float dx = xs[i] - px;
      const float dy = ys[i] - py;
      const float dz = zs[i] - pz;
      // exact numpy order, no fma contraction:
      const float d = __fadd_rn(__fadd_rn(__fmul_rn(dx, dx), __fmul_rn(dy, dy)),
                                __fmul_rn(dz, dz));
      const float m = fminf(mind[i], d);
      mind[i] = m;
      if (m > bestv) { bestv = m; besti = t + i * 512; }
    }

    // wave (64-lane) argmax reduce, tie -> lowest index
#pragma unroll
    for (int off = 32; off >= 1; off >>= 1) {
      const float ov = __shfl_xor(bestv, off, 64);
      const int   oi = __shfl_xor(besti, off, 64);
      if (ov > bestv || (ov == bestv && oi < besti)) { bestv = ov; besti = oi; }
    }
    if ((t & 63) == 0) {
      const int wid = t >> 6;
      s_v[par][wid] = bestv;
      s_i[par][wid] = besti;
    }
    __syncthreads();

    // all threads redundantly scan the 8 slots (broadcast LDS reads)
    float bv = s_v[par][0];
    int   bi = s_i[par][0];
#pragma unroll
    for (int w = 1; w < 8; ++w) {
      const float v = s_v[par][w];
      const int  ii = s_i[par][w];
      if (v > bv || (v == bv && ii < bi)) { bv = v; bi = ii; }
    }

    // uniform-address gather: one transaction, L2-hit
    const float* __restrict__ q = p + bi * 3;
    px = q[0]; py = q[1]; pz = q[2];

    if (t == 0) {
      out_inds_f[b * NPOINT + k] = (float)bi;
      const size_t o = ((size_t)b * NPOINT + k) * 3;
      out_newxyz[o + 0] = px; out_newxyz[o + 1] = py; out_newxyz[o + 2] = pz;
    }
    // no second barrier: parity double-buffer makes next iteration's slot
    // writes target the other buffer; a wave cannot wrap to this buffer
    // again without everyone passing the next barrier.
  }
}

// ---------------------------------------------------------------------------
// Transpose weights into [ic][oc] layout so MLP threads can float4-load
// 4 (or 8) output channels per K-step.
// ---------------------------------------------------------------------------
__global__ void wtrans_kernel(const float* __restrict__ W0,
                              const float* __restrict__ W1,
                              const float* __restrict__ W2,
                              float* __restrict__ w0t,
                              float* __restrict__ w1t,
                              float* __restrict__ w2t)
{
  const int t = blockIdx.x * blockDim.x + threadIdx.x;
  if (t < 64 * CIN) { const int oc = t / CIN, ic = t % CIN; w0t[ic * 64  + oc] = W0[t]; }
  if (t < 64 * 64)  { const int oc = t >> 6,  ic = t & 63;  w1t[ic * 64  + oc] = W1[t]; }
  if (t < 128 * 64) { const int oc = t / 64,  ic = t % 64;  w2t[ic * 128 + oc] = W2[t]; }
}

// ---------------------------------------------------------------------------
// Ball query: one wave per center. First NSAMPLE indices (ascending) with
// d2 < r^2; pad remaining slots with the first in-ball index.
// ---------------------------------------------------------------------------
__global__ __launch_bounds__(256) void ballquery_kernel(
    const float* __restrict__ xyz, const float* __restrict__ newxyz,
    int* __restrict__ ballidx)
{
  const int gw   = (blockIdx.x * 256 + threadIdx.x) >> 6;  // global wave = center
  const int lane = threadIdx.x & 63;
  const int b    = gw >> 10;
  const float R2 = (float)(0.3 * 0.3);   // fl32(0.09), matches numpy weak cast

  const float cx = newxyz[gw * 3 + 0];
  const float cy = newxyz[gw * 3 + 1];
  const float cz = newxyz[gw * 3 + 2];
  const float* __restrict__ p = xyz + (size_t)b * NPTS * 3;
  int* __restrict__ out = ballidx + (size_t)gw * NSAMPLE;

  int cnt = 0, first = -1;
  for (int base = 0; base < NPTS; base += 64) {
    const int n = base + lane;
    const float dx = p[n * 3 + 0] - cx;
    const float dy = p[n * 3 + 1] - cy;
    const float dz = p[n * 3 + 2] - cz;
    const float d = __fadd_rn(__fadd_rn(__fmul_rn(dx, dx), __fmul_rn(dy, dy)),
                              __fmul_rn(dz, dz));
    const bool in = d < R2;
    const unsigned long long m = __ballot(in);
    if (first < 0 && m) first = base + __ffsll(m) - 1;
    const int pos = __popcll(m & ((1ull << lane) - 1ull));
    if (in && cnt + pos < NSAMPLE) out[cnt + pos] = n;
    cnt += __popcll(m);
    if (cnt >= NSAMPLE) break;
  }
  const int c = cnt < NSAMPLE ? cnt : NSAMPLE;
  for (int j = c + lane; j < NSAMPLE; j += 64) out[j] = first;
}

// ---------------------------------------------------------------------------
// Grouping + SharedMLP (131->64->64->128, ReLU) + max-pool over samples.
// One block (256 threads) per center. x staged in LDS [ch][64]; weights read
// from global transposed layout; bias folded into acc init; ReLU once after
// the max-pool (monotone => commutes).
// ---------------------------------------------------------------------------
__global__ __launch_bounds__(256) void mlp_kernel(
    const float* __restrict__ xyz, const float* __restrict__ feat,
    const float* __restrict__ newxyz, const int* __restrict__ ballidx,
    const float* __restrict__ w0t, const float* __restrict__ b0,
    const float* __restrict__ w1t, const float* __restrict__ b1,
    const float* __restrict__ w2t, const float* __restrict__ b2,
    float* __restrict__ out_feat)
{
  __shared__ float sA[CIN * 64];   // x (131x64); reused as h2 (64x64)
  __shared__ float sB[64 * 64];    // h1
  __shared__ int   s_idx[NSAMPLE];

  const int blk = blockIdx.x;
  const int b = blk >> 10, pc = blk & 1023;
  const int t = threadIdx.x;

  if (t < NSAMPLE) s_idx[t] = ballidx[(size_t)blk * NSAMPLE + t];
  __syncthreads();

  const int s = t & 63, cg = t >> 6;
  const int is = s_idx[s];
  const float* __restrict__ pb = xyz + (size_t)b * NPTS * 3;
  if (cg == 0) {
    const float cx = newxyz[blk * 3 + 0];
    const float cy = newxyz[blk * 3 + 1];
    const float cz = newxyz[blk * 3 + 2];
    sA[0 * 64 + s] = pb[is * 3 + 0] - cx;
    sA[1 * 64 + s] = pb[is * 3 + 1] - cy;
    sA[2 * 64 + s] = pb[is * 3 + 2] - cz;
  }
  const float* __restrict__ fb = feat + (size_t)b * NCH * NPTS;
  for (int c = cg; c < NCH; c += 4)
    sA[(3 + c) * 64 + s] = fb[(size_t)c * NPTS + is];
  __syncthreads();

  const int s0  = (t & 15) * 4;   // 4 samples
  const int oc0 = (t >> 4) * 4;   // 4 out-channels (layers 1,2)

  // ---- layer 1: CIN -> 64  (sA -> sB)
  {
    float acc[4][4];
#pragma unroll
    for (int j = 0; j < 4; ++j) {
      const float bj = b0[oc0 + j];
#pragma unroll
      for (int i = 0; i < 4; ++i) acc[i][j] = bj;
    }
    for (int ic = 0; ic < CIN; ++ic) {
      const float4 xv = *(const float4*)&sA[ic * 64 + s0];
      const float4 wv = *(const float4*)&w0t[ic * 64 + oc0];
      const float xr[4] = {xv.x, xv.y, xv.z, xv.w};
      const float wr[4] = {wv.x, wv.y, wv.z, wv.w};
#pragma unroll
      for (int i = 0; i < 4; ++i)
#pragma unroll
        for (int j = 0; j < 4; ++j) acc[i][j] += xr[i] * wr[j];
    }
#pragma unroll
    for (int j = 0; j < 4; ++j) {
      float4 r;
      r.x = fmaxf(acc[0][j], 0.f); r.y = fmaxf(acc[1][j], 0.f);
      r.z = fmaxf(acc[2][j], 0.f); r.w = fmaxf(acc[3][j], 0.f);
      *(float4*)&sB[(oc0 + j) * 64 + s0] = r;
    }
  }
  __syncthreads();

  // ---- layer 2: 64 -> 64  (sB -> sA, x is dead)
  {
    float acc[4][4];
#pragma unroll
    for (int j = 0; j < 4; ++j) {
      const float bj = b1[oc0 + j];
#pragma unroll
      for (int i = 0; i < 4; ++i) acc[i][j] = bj;
    }
    for (int ic = 0; ic < 64; ++ic) {
      const float4 xv = *(const float4*)&sB[ic * 64 + s0];
      const float4 wv = *(const float4*)&w1t[ic * 64 + oc0];
      const float xr[4] = {xv.x, xv.y, xv.z, xv.w};
      const float wr[4] = {wv.x, wv.y, wv.z, wv.w};
#pragma unroll
      for (int i = 0; i < 4; ++i)
#pragma unroll
        for (int j = 0; j < 4; ++j) acc[i][j] += xr[i] * wr[j];
    }
#pragma unroll
    for (int j = 0; j < 4; ++j) {
      float4 r;
      r.x = fmaxf(acc[0][j], 0.f); r.y = fmaxf(acc[1][j], 0.f);
      r.z = fmaxf(acc[2][j], 0.f); r.w = fmaxf(acc[3][j], 0.f);
      *(float4*)&sA[(oc0 + j) * 64 + s0] = r;
    }
  }
  __syncthreads();

  // ---- layer 3: 64 -> 128 + max-pool over 64 samples
  const int oc8 = (t >> 4) * 8;
  float acc[4][8];
#pragma unroll
  for (int j = 0; j < 8; ++j) {
    const float bj = b2[oc8 + j];
#pragma unroll
    for (int i = 0; i < 4; ++i) acc[i][j] = bj;
  }
  for (int ic = 0; ic < 64; ++ic) {
    const float4 xv  = *(const float4*)&sA[ic * 64 + s0];
    const float4 wlo = *(const float4*)&w2t[ic * 128 + oc8];
    const float4 whi = *(const float4*)&w2t[ic * 128 + oc8 + 4];
    const float xr[4] = {xv.x, xv.y, xv.z, xv.w};
    const float wr[8] = {wlo.x, wlo.y, wlo.z, wlo.w, whi.x, whi.y, whi.z, whi.w};
#pragma unroll
    for (int i = 0; i < 4; ++i)
#pragma unroll
      for (int j = 0; j < 8; ++j) acc[i][j] += xr[i] * wr[j];
  }
  float m[8];
#pragma unroll
  for (int j = 0; j < 8; ++j)
    m[j] = fmaxf(fmaxf(acc[0][j], acc[1][j]), fmaxf(acc[2][j], acc[3][j]));
#pragma unroll
  for (int off = 8; off >= 1; off >>= 1) {
#pragma unroll
    for (int j = 0; j < 8; ++j)
      m[j] = fmaxf(m[j], __shfl_xor(m[j], off, 64));
  }
  if ((t & 15) == 0) {
#pragma unroll
    for (int j = 0; j < 8; ++j)
      out_feat[((size_t)b * NCH + oc8 + j) * NPOINT + pc] = fmaxf(m[j], 0.f);
  }
}

// ---------------------------------------------------------------------------
extern "C" void kernel_launch(void* const* d_in, const int* in_sizes, int n_in,
                              void* d_out, int out_size, void* d_ws, size_t ws_size,
                              hipStream_t stream)
{
  const float* xyz  = (const float*)d_in[0];
  const float* feat = (const float*)d_in[1];
  const float* W0   = (const float*)d_in[2];
  const float* b0   = (const float*)d_in[3];
  const float* W1   = (const float*)d_in[4];
  const float* b1   = (const float*)d_in[5];
  const float* W2   = (const float*)d_in[6];
  const float* b2   = (const float*)d_in[7];

  float* out_newxyz = (float*)d_out;                               // 8*1024*3
  float* out_feat   = out_newxyz + (size_t)BATCH * NPOINT * 3;     // 8*128*1024
  float* out_inds_f = out_feat + (size_t)BATCH * NCH * NPOINT;     // 8*1024

  char* ws = (char*)d_ws;
  int*   ballidx = (int*)ws;                                       // 2 MB
  float* w0t = (float*)(ws + (size_t)BATCH * NPOINT * NSAMPLE * 4);
  float* w1t = w0t + 64 * CIN;
  float* w2t = w1t + 64 * 64;

  fps_kernel<<<dim3(BATCH), dim3(512), 0, stream>>>(xyz, out_newxyz, out_inds_f);
  wtrans_kernel<<<dim3((64 * CIN + 255) / 256), dim3(256), 0, stream>>>(
      W0, W1, W2, w0t, w1t, w2t);
  ballquery_kernel<<<dim3(BATCH * NPOINT / 4), dim3(256), 0, stream>>>(
      xyz, out_newxyz, ballidx);
  mlp_kernel<<<dim3(BATCH * NPOINT), dim3(256), 0, stream>>>(
      xyz, feat, out_newxyz, ballidx, w0t, b0, w1t, b1, w2t, b2, out_feat);
}

// Round 5
// 2443.572 us; speedup vs baseline: 1.4286x; 1.1731x over previous
//
#include <hip/hip_runtime.h>

#define BATCH   8
#define NPTS    16384
#define NCH     128
#define NPOINT  1024
#define NSAMPLE 64
#define CIN     131   // 3 + NCH

#define FPS_SUBS     4                     // blocks per batch (same XCD)
#define FPS_THREADS  512
#define FPS_CHUNK    (NPTS / FPS_SUBS)     // 4096 points per block
#define FPS_PPT      (FPS_CHUNK / FPS_THREADS)  // 8 points per thread

typedef unsigned long long u64;

// ---------------------------------------------------------------------------
// Multi-block FPS: 4 blocks per batch, spin-synced through same-XCD L2.
// Bit-exact vs numpy: d = ((dx*dx+dy*dy)+dz*dz), no FMA contraction, fminf,
// argmax first-occurrence (all tie-breaks -> lowest flat index).
// Packed u64 slot: [59:50]=iter tag, [49:18]=f32 bits of dist (>=0 so uint
// order == float order), [17:0]=idx ^ 0x3FFFF (max-reduce -> lowest idx).
// Parity double-buffer + per-call memset makes the spin protocol race-free
// under graph replay.
// ---------------------------------------------------------------------------
__global__ __launch_bounds__(FPS_THREADS) void fps_mb_kernel(
    const float* __restrict__ xyz, float* __restrict__ out_newxyz,
    float* __restrict__ out_inds_f, u64* __restrict__ sync)
{
  const int bid = blockIdx.x;
  const int b   = bid & 7;        // batch == XCD (round-robin dispatch)
  const int sub = bid >> 3;       // 0..3
  const int t   = threadIdx.x;
  const int lane = t & 63, wid = t >> 6;
  const float* __restrict__ p = xyz + (size_t)b * NPTS * 3;
  const int base = sub * FPS_CHUNK;

  float xs[FPS_PPT], ys[FPS_PPT], zs[FPS_PPT], mind[FPS_PPT];
#pragma unroll
  for (int i = 0; i < FPS_PPT; ++i) {
    const int n = base + t + i * FPS_THREADS;   // coalesced per wave
    xs[i] = p[n * 3 + 0];
    ys[i] = p[n * 3 + 1];
    zs[i] = p[n * 3 + 2];
    mind[i] = 1e10f;
  }

  __shared__ u64 s_w[FPS_THREADS / 64];
  __shared__ int s_bi;

  float px = p[0], py = p[1], pz = p[2];
  if (sub == 0 && t == 0) {
    out_inds_f[b * NPOINT] = 0.0f;
    const size_t o = (size_t)b * NPOINT * 3;
    out_newxyz[o + 0] = px; out_newxyz[o + 1] = py; out_newxyz[o + 2] = pz;
  }

  u64* __restrict__ slots = sync + b * (2 * FPS_SUBS);   // [par][sub]

  for (int k = 1; k < NPOINT; ++k) {
    const int par = k & 1;

    // ---- local min-dist update + argmax over this block's 4096 points
    float bestv = -1.0f;
    int   besti = 0;
#pragma unroll
    for (int i = 0; i < FPS_PPT; ++i) {
      const float dx = xs[i] - px;
      const float dy = ys[i] - py;
      const float dz = zs[i] - pz;
      // exact numpy order, no fma contraction:
      const float d = __fadd_rn(__fadd_rn(__fmul_rn(dx, dx), __fmul_rn(dy, dy)),
                                __fmul_rn(dz, dz));
      const float m = fminf(mind[i], d);
      mind[i] = m;
      if (m > bestv) { bestv = m; besti = base + t + i * FPS_THREADS; }
    }

    // ---- pack and wave-reduce (u64 max == (val max, idx min))
    u64 pk = ((u64)k << 50) | ((u64)__float_as_uint(bestv) << 18)
           | (u64)(besti ^ 0x3FFFF);
#pragma unroll
    for (int off = 32; off >= 1; off >>= 1) {
      const u64 o_ = __shfl_xor(pk, off, 64);
      pk = (o_ > pk) ? o_ : pk;
    }
    if (lane == 0) s_w[wid] = pk;
    __syncthreads();

    // ---- block leader publishes block-best to its L2 slot
    if (t == 0) {
      u64 w = s_w[0];
#pragma unroll
      for (int i = 1; i < FPS_THREADS / 64; ++i) {
        const u64 x = s_w[i];
        w = (x > w) ? x : w;
      }
      __hip_atomic_store(&slots[par * FPS_SUBS + sub], w,
                         __ATOMIC_RELEASE, __HIP_MEMORY_SCOPE_AGENT);
    }

    // ---- wave 0 polls all 4 sub-slots until they carry tag k
    if (wid == 0) {
      u64 v = 0;
      if (lane < FPS_SUBS) {
        do {
          v = __hip_atomic_load(&slots[par * FPS_SUBS + lane],
                                __ATOMIC_ACQUIRE, __HIP_MEMORY_SCOPE_AGENT);
        } while ((int)(v >> 50) != k);
      }
      u64 o1 = __shfl_xor(v, 1, 64); v = (o1 > v) ? o1 : v;
      u64 o2 = __shfl_xor(v, 2, 64); v = (o2 > v) ? o2 : v;
      if (lane == 0) s_bi = (int)((~v) & 0x3FFFF);
    }
    __syncthreads();

    // ---- everyone picks up the winner; uniform (broadcast) coord load
    const int bi = s_bi;
    const float* __restrict__ q = p + bi * 3;
    px = q[0]; py = q[1]; pz = q[2];

    if (sub == 0 && t == 0) {
      out_inds_f[b * NPOINT + k] = (float)bi;
      const size_t o = ((size_t)b * NPOINT + k) * 3;
      out_newxyz[o + 0] = px; out_newxyz[o + 1] = py; out_newxyz[o + 2] = pz;
    }
  }
}

// ---------------------------------------------------------------------------
// Transpose weights into [ic][oc] layout so MLP threads can float4-load
// 4 (or 8) output channels per K-step.
// ---------------------------------------------------------------------------
__global__ void wtrans_kernel(const float* __restrict__ W0,
                              const float* __restrict__ W1,
                              const float* __restrict__ W2,
                              float* __restrict__ w0t,
                              float* __restrict__ w1t,
                              float* __restrict__ w2t)
{
  const int t = blockIdx.x * blockDim.x + threadIdx.x;
  if (t < 64 * CIN) { const int oc = t / CIN, ic = t % CIN; w0t[ic * 64  + oc] = W0[t]; }
  if (t < 64 * 64)  { const int oc = t >> 6,  ic = t & 63;  w1t[ic * 64  + oc] = W1[t]; }
  if (t < 128 * 64) { const int oc = t / 64,  ic = t % 64;  w2t[ic * 128 + oc] = W2[t]; }
}

// ---------------------------------------------------------------------------
// Ball query: one wave per center. First NSAMPLE indices (ascending) with
// d2 < r^2; pad remaining slots with the first in-ball index.
// ---------------------------------------------------------------------------
__global__ __launch_bounds__(256) void ballquery_kernel(
    const float* __restrict__ xyz, const float* __restrict__ newxyz,
    int* __restrict__ ballidx)
{
  const int gw   = (blockIdx.x * 256 + threadIdx.x) >> 6;  // global wave = center
  const int lane = threadIdx.x & 63;
  const int b    = gw >> 10;
  const float R2 = (float)(0.3 * 0.3);   // fl32(0.09), matches numpy weak cast

  const float cx = newxyz[gw * 3 + 0];
  const float cy = newxyz[gw * 3 + 1];
  const float cz = newxyz[gw * 3 + 2];
  const float* __restrict__ p = xyz + (size_t)b * NPTS * 3;
  int* __restrict__ out = ballidx + (size_t)gw * NSAMPLE;

  int cnt = 0, first = -1;
  for (int base = 0; base < NPTS; base += 64) {
    const int n = base + lane;
    const float dx = p[n * 3 + 0] - cx;
    const float dy = p[n * 3 + 1] - cy;
    const float dz = p[n * 3 + 2] - cz;
    const float d = __fadd_rn(__fadd_rn(__fmul_rn(dx, dx), __fmul_rn(dy, dy)),
                              __fmul_rn(dz, dz));
    const bool in = d < R2;
    const unsigned long long m = __ballot(in);
    if (first < 0 && m) first = base + __ffsll(m) - 1;
    const int pos = __popcll(m & ((1ull << lane) - 1ull));
    if (in && cnt + pos < NSAMPLE) out[cnt + pos] = n;
    cnt += __popcll(m);
    if (cnt >= NSAMPLE) break;
  }
  const int c = cnt < NSAMPLE ? cnt : NSAMPLE;
  for (int j = c + lane; j < NSAMPLE; j += 64) out[j] = first;
}

// ---------------------------------------------------------------------------
// Grouping + SharedMLP (131->64->64->128, ReLU) + max-pool over samples.
// One block (256 threads) per center. x staged in LDS [ch][64]; weights read
// from global transposed layout; bias folded into acc init; ReLU once after
// the max-pool (monotone => commutes).
// ---------------------------------------------------------------------------
__global__ __launch_bounds__(256) void mlp_kernel(
    const float* __restrict__ xyz, const float* __restrict__ feat,
    const float* __restrict__ newxyz, const int* __restrict__ ballidx,
    const float* __restrict__ w0t, const float* __restrict__ b0,
    const float* __restrict__ w1t, const float* __restrict__ b1,
    const float* __restrict__ w2t, const float* __restrict__ b2,
    float* __restrict__ out_feat)
{
  __shared__ float sA[CIN * 64];   // x (131x64); reused as h2 (64x64)
  __shared__ float sB[64 * 64];    // h1
  __shared__ int   s_idx[NSAMPLE];

  const int blk = blockIdx.x;
  const int b = blk >> 10, pc = blk & 1023;
  const int t = threadIdx.x;

  if (t < NSAMPLE) s_idx[t] = ballidx[(size_t)blk * NSAMPLE + t];
  __syncthreads();

  const int s = t & 63, cg = t >> 6;
  const int is = s_idx[s];
  const float* __restrict__ pb = xyz + (size_t)b * NPTS * 3;
  if (cg == 0) {
    const float cx = newxyz[blk * 3 + 0];
    const float cy = newxyz[blk * 3 + 1];
    const float cz = newxyz[blk * 3 + 2];
    sA[0 * 64 + s] = pb[is * 3 + 0] - cx;
    sA[1 * 64 + s] = pb[is * 3 + 1] - cy;
    sA[2 * 64 + s] = pb[is * 3 + 2] - cz;
  }
  const float* __restrict__ fb = feat + (size_t)b * NCH * NPTS;
  for (int c = cg; c < NCH; c += 4)
    sA[(3 + c) * 64 + s] = fb[(size_t)c * NPTS + is];
  __syncthreads();

  const int s0  = (t & 15) * 4;   // 4 samples
  const int oc0 = (t >> 4) * 4;   // 4 out-channels (layers 1,2)

  // ---- layer 1: CIN -> 64  (sA -> sB)
  {
    float acc[4][4];
#pragma unroll
    for (int j = 0; j < 4; ++j) {
      const float bj = b0[oc0 + j];
#pragma unroll
      for (int i = 0; i < 4; ++i) acc[i][j] = bj;
    }
    for (int ic = 0; ic < CIN; ++ic) {
      const float4 xv = *(const float4*)&sA[ic * 64 + s0];
      const float4 wv = *(const float4*)&w0t[ic * 64 + oc0];
      const float xr[4] = {xv.x, xv.y, xv.z, xv.w};
      const float wr[4] = {wv.x, wv.y, wv.z, wv.w};
#pragma unroll
      for (int i = 0; i < 4; ++i)
#pragma unroll
        for (int j = 0; j < 4; ++j) acc[i][j] += xr[i] * wr[j];
    }
#pragma unroll
    for (int j = 0; j < 4; ++j) {
      float4 r;
      r.x = fmaxf(acc[0][j], 0.f); r.y = fmaxf(acc[1][j], 0.f);
      r.z = fmaxf(acc[2][j], 0.f); r.w = fmaxf(acc[3][j], 0.f);
      *(float4*)&sB[(oc0 + j) * 64 + s0] = r;
    }
  }
  __syncthreads();

  // ---- layer 2: 64 -> 64  (sB -> sA, x is dead)
  {
    float acc[4][4];
#pragma unroll
    for (int j = 0; j < 4; ++j) {
      const float bj = b1[oc0 + j];
#pragma unroll
      for (int i = 0; i < 4; ++i) acc[i][j] = bj;
    }
    for (int ic = 0; ic < 64; ++ic) {
      const float4 xv = *(const float4*)&sB[ic * 64 + s0];
      const float4 wv = *(const float4*)&w1t[ic * 64 + oc0];
      const float xr[4] = {xv.x, xv.y, xv.z, xv.w};
      const float wr[4] = {wv.x, wv.y, wv.z, wv.w};
#pragma unroll
      for (int i = 0; i < 4; ++i)
#pragma unroll
        for (int j = 0; j < 4; ++j) acc[i][j] += xr[i] * wr[j];
    }
#pragma unroll
    for (int j = 0; j < 4; ++j) {
      float4 r;
      r.x = fmaxf(acc[0][j], 0.f); r.y = fmaxf(acc[1][j], 0.f);
      r.z = fmaxf(acc[2][j], 0.f); r.w = fmaxf(acc[3][j], 0.f);
      *(float4*)&sA[(oc0 + j) * 64 + s0] = r;
    }
  }
  __syncthreads();

  // ---- layer 3: 64 -> 128 + max-pool over 64 samples
  const int oc8 = (t >> 4) * 8;
  float acc[4][8];
#pragma unroll
  for (int j = 0; j < 8; ++j) {
    const float bj = b2[oc8 + j];
#pragma unroll
    for (int i = 0; i < 4; ++i) acc[i][j] = bj;
  }
  for (int ic = 0; ic < 64; ++ic) {
    const float4 xv  = *(const float4*)&sA[ic * 64 + s0];
    const float4 wlo = *(const float4*)&w2t[ic * 128 + oc8];
    const float4 whi = *(const float4*)&w2t[ic * 128 + oc8 + 4];
    const float xr[4] = {xv.x, xv.y, xv.z, xv.w};
    const float wr[8] = {wlo.x, wlo.y, wlo.z, wlo.w, whi.x, whi.y, whi.z, whi.w};
#pragma unroll
    for (int i = 0; i < 4; ++i)
#pragma unroll
      for (int j = 0; j < 8; ++j) acc[i][j] += xr[i] * wr[j];
  }
  float m[8];
#pragma unroll
  for (int j = 0; j < 8; ++j)
    m[j] = fmaxf(fmaxf(acc[0][j], acc[1][j]), fmaxf(acc[2][j], acc[3][j]));
#pragma unroll
  for (int off = 8; off >= 1; off >>= 1) {
#pragma unroll
    for (int j = 0; j < 8; ++j)
      m[j] = fmaxf(m[j], __shfl_xor(m[j], off, 64));
  }
  if ((t & 15) == 0) {
#pragma unroll
    for (int j = 0; j < 8; ++j)
      out_feat[((size_t)b * NCH + oc8 + j) * NPOINT + pc] = fmaxf(m[j], 0.f);
  }
}

// ---------------------------------------------------------------------------
extern "C" void kernel_launch(void* const* d_in, const int* in_sizes, int n_in,
                              void* d_out, int out_size, void* d_ws, size_t ws_size,
                              hipStream_t stream)
{
  const float* xyz  = (const float*)d_in[0];
  const float* feat = (const float*)d_in[1];
  const float* W0   = (const float*)d_in[2];
  const float* b0   = (const float*)d_in[3];
  const float* W1   = (const float*)d_in[4];
  const float* b1   = (const float*)d_in[5];
  const float* W2   = (const float*)d_in[6];
  const float* b2   = (const float*)d_in[7];

  float* out_newxyz = (float*)d_out;                               // 8*1024*3
  float* out_feat   = out_newxyz + (size_t)BATCH * NPOINT * 3;     // 8*128*1024
  float* out_inds_f = out_feat + (size_t)BATCH * NCH * NPOINT;     // 8*1024

  char* ws = (char*)d_ws;
  int*   ballidx = (int*)ws;                                       // 2 MB
  float* w0t = (float*)(ws + (size_t)BATCH * NPOINT * NSAMPLE * 4);
  float* w1t = w0t + 64 * CIN;
  float* w2t = w1t + 64 * 64;
  u64*   fsync = (u64*)(w2t + 64 * 128);   // 8 batches * 2 par * 4 subs = 64 u64

  hipMemsetAsync(fsync, 0, BATCH * 2 * FPS_SUBS * sizeof(u64), stream);
  fps_mb_kernel<<<dim3(BATCH * FPS_SUBS), dim3(FPS_THREADS), 0, stream>>>(
      xyz, out_newxyz, out_inds_f, fsync);
  wtrans_kernel<<<dim3((64 * CIN + 255) / 256), dim3(256), 0, stream>>>(
      W0, W1, W2, w0t, w1t, w2t);
  ballquery_kernel<<<dim3(BATCH * NPOINT / 4), dim3(256), 0, stream>>>(
      xyz, out_newxyz, ballidx);
  mlp_kernel<<<dim3(BATCH * NPOINT), dim3(256), 0, stream>>>(
      xyz, feat, out_newxyz, ballidx, w0t, b0, w1t, b1, w2t, b2, out_feat);
}